// Round 2
// baseline (693.415 us; speedup 1.0000x reference)
//
#include <hip/hip_runtime.h>
#include <hip/hip_bf16.h>
#include <math.h>

typedef __hip_bfloat16 bf16;
typedef __attribute__((ext_vector_type(4))) float f32x4;
typedef __attribute__((ext_vector_type(8))) __bf16 bf16x8;

static constexpr int HID    = 2560;
static constexpr int LRUD   = 2560;
static constexpr int HEADSN = 10;
static constexpr int BWID   = 256;          // LRU / HEADS
static constexpr int SEQL   = 4096;
static constexpr int BATCHN = 2;
static constexpr int NTOK   = BATCHN * SEQL;   // 8192
static constexpr int NCHUNK = 128;             // scan chunks per sequence
static constexpr int CHLEN  = 32;              // NCHUNK*CHLEN == SEQL

#define GAS __attribute__((address_space(1)))
#define LAS __attribute__((address_space(3)))

__device__ __forceinline__ void async_copy16(void* lds, const void* g) {
  // global -> LDS direct DMA, 16B per lane; LDS dest is wave-uniform base + lane*16
  __builtin_amdgcn_global_load_lds((const GAS unsigned int*)g,
                                   (LAS unsigned int*)lds, 16, 0, 0);
}

// ---------------------------------------------------------------------------
// Generic bf16 MFMA GEMM:  C[m][n] = epi( sum_k A[m][k] * B[n][k] + bias[n] )
// A row-major [M][lda], B row-major [N][ldb] (i.e. weight W[N][K]).
// 128x128 tile, BK=64, 4 waves (2x2), each wave 4x4 frags of 16x16x32.
// LDS XOR-swizzled: physical byte = r*128 + (cb ^ ((r&7)<<4)); staging uses
// linear LDS dest + inverse-swizzled global source (global_load_lds rule #21).
// EPI: 0 = fp32 out (bias), 1 = bf16 gelu_tanh(x+bias), 2 = bf16 (x+bias),
//      3 = bf16 sigmoid(x+bias)
// blockIdx.z strides (aZ,bZ,cZ in elements) support per-head block-diag GEMMs.
// ---------------------------------------------------------------------------
template<int EPI>
__global__ __launch_bounds__(256)
void gemm_kernel(const bf16* __restrict__ A, int lda, long long aZ,
                 const bf16* __restrict__ Bw, int ldb, long long bZ,
                 const float* __restrict__ bias,
                 void* __restrict__ Cp, int ldc, long long cZ,
                 int K)
{
  __shared__ __align__(16) bf16 As[128 * 64];
  __shared__ __align__(16) bf16 Bs[128 * 64];

  const int tid  = threadIdx.x;
  const int wave = tid >> 6;
  const int lane = tid & 63;
  const int wy   = wave >> 1;     // wave row (m)
  const int wx   = wave & 1;      // wave col (n)
  const int m0   = blockIdx.y * 128;
  const int n0   = blockIdx.x * 128;

  A  += (long long)blockIdx.z * aZ;
  Bw += (long long)blockIdx.z * bZ;

  f32x4 acc[4][4] = {};

  const int srow = tid >> 3;           // 0..31 within a staging round
  const int spb  = (tid & 7) * 16;     // physical byte offset within 128B row

  for (int k0 = 0; k0 < K; k0 += 64) {
#pragma unroll
    for (int rd = 0; rd < 4; ++rd) {
      const int r  = rd * 32 + srow;                 // tile row 0..127
      const int cb = spb ^ ((r & 7) << 4);           // logical byte in row (inverse swizzle)
      async_copy16(&As[rd * 2048 + wave * 512],
                   A + (size_t)(m0 + r) * lda + k0 + (cb >> 1));
      async_copy16(&Bs[rd * 2048 + wave * 512],
                   Bw + (size_t)(n0 + r) * ldb + k0 + (cb >> 1));
    }
    __syncthreads();   // drains vmcnt -> staged data visible

#pragma unroll
    for (int ks = 0; ks < 2; ++ks) {
      bf16x8 af[4], bfr[4];
      const int cb = ks * 64 + (lane >> 4) * 16;     // logical byte: k = ks*32 + (lane>>4)*8
#pragma unroll
      for (int f = 0; f < 4; ++f) {
        const int ra = wy * 64 + f * 16 + (lane & 15);
        af[f] = *(const bf16x8*)((const char*)As + ra * 128 + (cb ^ ((ra & 7) << 4)));
        const int rb = wx * 64 + f * 16 + (lane & 15);
        bfr[f] = *(const bf16x8*)((const char*)Bs + rb * 128 + (cb ^ ((rb & 7) << 4)));
      }
#pragma unroll
      for (int fm = 0; fm < 4; ++fm)
#pragma unroll
        for (int fn = 0; fn < 4; ++fn)
          acc[fm][fn] = __builtin_amdgcn_mfma_f32_16x16x32_bf16(af[fm], bfr[fn], acc[fm][fn], 0, 0, 0);
    }
    __syncthreads();   // protect LDS before next overwrite
  }

  // epilogue: C/D layout (verified): col = lane&15, row = (lane>>4)*4 + reg
  const int mrb = (lane >> 4) * 4;
  const int ncc = lane & 15;
#pragma unroll
  for (int fm = 0; fm < 4; ++fm) {
#pragma unroll
    for (int fn = 0; fn < 4; ++fn) {
      const int n  = n0 + wx * 64 + fn * 16 + ncc;
      const float bv = bias[n];
#pragma unroll
      for (int r = 0; r < 4; ++r) {
        const int m = m0 + wy * 64 + fm * 16 + mrb + r;
        const size_t idx = (size_t)blockIdx.z * cZ + (size_t)m * ldc + n;
        float v = acc[fm][fn][r] + bv;
        if constexpr (EPI == 0) {
          ((float*)Cp)[idx] = v;
        } else if constexpr (EPI == 1) {
          const float t = tanhf(0.7978845608028654f * (v + 0.044715f * v * v * v));
          ((bf16*)Cp)[idx] = __float2bfloat16(0.5f * v * (1.0f + t));
        } else if constexpr (EPI == 2) {
          ((bf16*)Cp)[idx] = __float2bfloat16(v);
        } else {
          ((bf16*)Cp)[idx] = __float2bfloat16(1.0f / (1.0f + expf(-v)));
        }
      }
    }
  }
}

// ---------------------------------------------------------------------------
__global__ __launch_bounds__(256)
void f32_to_bf16_kernel(const float* __restrict__ in, bf16* __restrict__ out, int n) {
  const int i = (blockIdx.x * 256 + threadIdx.x) * 4;
  if (i + 4 <= n) {
    const float4 v = *(const float4*)(in + i);
    out[i + 0] = __float2bfloat16(v.x);
    out[i + 1] = __float2bfloat16(v.y);
    out[i + 2] = __float2bfloat16(v.z);
    out[i + 3] = __float2bfloat16(v.w);
  }
}

// depthwise causal conv, width 4: out[t] = b + sum_k x[t-3+k]*w[c][k]
__global__ __launch_bounds__(256)
void conv_kernel(const bf16* __restrict__ Xb, const float* __restrict__ cw,
                 const float* __restrict__ cbias, bf16* __restrict__ out) {
  const int c = blockIdx.x * 256 + threadIdx.x;
  const int t = blockIdx.y;
  const int b = blockIdx.z;
  const size_t base = ((size_t)b * SEQL + t) * LRUD + c;
  float acc = cbias[c] + __bfloat162float(Xb[base]) * cw[c * 4 + 3];
  if (t >= 1) acc += __bfloat162float(Xb[base - (size_t)LRUD])     * cw[c * 4 + 2];
  if (t >= 2) acc += __bfloat162float(Xb[base - (size_t)2 * LRUD]) * cw[c * 4 + 1];
  if (t >= 3) acc += __bfloat162float(Xb[base - (size_t)3 * LRUD]) * cw[c * 4 + 0];
  out[base] = __float2bfloat16(acc);
}

// shared recurrence-input recompute: a = exp(-8*ga*softplus(ap)); x = conv*gx*sqrt(1-a^2)
// reset at t==0: a=0, mult=1. Identical fp32 expressions in scan1 and scan3.
__device__ __forceinline__ void compute_ax(float conv, float gx, float ga, float sp,
                                           int t, float& a, float& x) {
  const float la  = -8.f * ga * sp;
  a               = expf(la);
  const float asq = expf(2.f * la);
  float mult      = sqrtf(fmaxf(1.f - asq, 0.f));
  if (t == 0) { a = 0.f; mult = 1.f; }
  x = conv * gx * mult;
}

// scan phase 1: per-chunk composition (A = prod a, X = local scan end value)
__global__ __launch_bounds__(256)
void scan1_kernel(const bf16* __restrict__ conv, const bf16* __restrict__ gxb,
                  const bf16* __restrict__ gab, const float* __restrict__ a_param,
                  float* __restrict__ cA, float* __restrict__ cX) {
  const int c     = blockIdx.x * 256 + threadIdx.x;
  const int chunk = blockIdx.y;
  const int b     = blockIdx.z;
  const float ap  = a_param[c];
  const float sp  = (ap > 20.f) ? ap : log1pf(expf(ap));
  size_t base = ((size_t)b * SEQL + (size_t)chunk * CHLEN) * LRUD + c;
  float A = 1.f, X = 0.f;
  for (int tl = 0; tl < CHLEN; ++tl) {
    float a, x;
    compute_ax(__bfloat162float(conv[base]), __bfloat162float(gxb[base]),
               __bfloat162float(gab[base]), sp, chunk * CHLEN + tl, a, x);
    X = a * X + x;
    A *= a;
    base += LRUD;
  }
  const size_t ci = ((size_t)b * NCHUNK + chunk) * LRUD + c;
  cA[ci] = A;
  cX[ci] = X;
}

// scan phase 2: sequential carry across chunks per channel (tiny)
__global__ __launch_bounds__(256)
void scan2_kernel(const float* __restrict__ cA, const float* __restrict__ cX,
                  const float* __restrict__ prev_h, float* __restrict__ pref) {
  const int g = blockIdx.x * 256 + threadIdx.x;   // 0..BATCH*LRU-1
  const int b = g / LRUD;
  const int c = g % LRUD;
  float h = prev_h[g];
  for (int ch = 0; ch < NCHUNK; ++ch) {
    const size_t ci = ((size_t)b * NCHUNK + ch) * LRUD + c;
    pref[ci] = h;
    h = cA[ci] * h + cX[ci];
  }
}

// scan phase 3: replay chunk with incoming prefix, multiply by y_branch -> Hm (bf16)
// hm may alias conv (read happens before write at the same slot within a thread).
__global__ __launch_bounds__(256)
void scan3_kernel(const bf16* __restrict__ conv, const bf16* __restrict__ gxb,
                  const bf16* __restrict__ gab, const float* __restrict__ a_param,
                  const float* __restrict__ pref, const bf16* __restrict__ yb,
                  bf16* __restrict__ hm) {
  const int c     = blockIdx.x * 256 + threadIdx.x;
  const int chunk = blockIdx.y;
  const int b     = blockIdx.z;
  const float ap  = a_param[c];
  const float sp  = (ap > 20.f) ? ap : log1pf(expf(ap));
  float h = pref[((size_t)b * NCHUNK + chunk) * LRUD + c];
  size_t base = ((size_t)b * SEQL + (size_t)chunk * CHLEN) * LRUD + c;
  for (int tl = 0; tl < CHLEN; ++tl) {
    float a, x;
    compute_ax(__bfloat162float(conv[base]), __bfloat162float(gxb[base]),
               __bfloat162float(gab[base]), sp, chunk * CHLEN + tl, a, x);
    h = a * h + x;
    hm[base] = __float2bfloat16(h * __bfloat162float(yb[base]));
    base += LRUD;
  }
}

// ---------------------------------------------------------------------------
extern "C" void kernel_launch(void* const* d_in, const int* in_sizes, int n_in,
                              void* d_out, int out_size, void* d_ws, size_t ws_size,
                              hipStream_t stream) {
  const float* x_in    = (const float*)d_in[0];
  // d_in[1] = position_ids: arange(S) per batch -> reset iff t==0; not read.
  const float* prev_h  = (const float*)d_in[2];
  const float* w_y     = (const float*)d_in[3];
  const float* b_y     = (const float*)d_in[4];
  const float* w_x     = (const float*)d_in[5];
  const float* b_x     = (const float*)d_in[6];
  const float* w_out   = (const float*)d_in[7];
  const float* b_out   = (const float*)d_in[8];
  const float* conv_w  = (const float*)d_in[9];
  const float* conv_b  = (const float*)d_in[10];
  const float* a_param = (const float*)d_in[11];
  const float* ig_w    = (const float*)d_in[12];
  const float* ig_b    = (const float*)d_in[13];
  const float* ag_w    = (const float*)d_in[14];
  const float* ag_b    = (const float*)d_in[15];

  // ---- workspace layout (~134 MB total; Round-1 crash suspect was 385 MB overflow)
  char* ws = (char*)d_ws;
  size_t off = 0;
  auto alloc = [&](size_t bytes) -> char* {
    char* p = ws + off;
    off += (bytes + 255) & ~(size_t)255;
    return p;
  };
  bf16*  Xbf  = (bf16*)alloc((size_t)NTOK * HID * 2);     // input bf16; Gx alias later
  bf16*  Wyb  = (bf16*)alloc((size_t)LRUD * HID * 2);
  bf16*  Wxb  = (bf16*)alloc((size_t)LRUD * HID * 2);
  bf16*  Wob  = (bf16*)alloc((size_t)HID * LRUD * 2);
  bf16*  IGb  = (bf16*)alloc((size_t)BWID * LRUD * 2);
  bf16*  AGb  = (bf16*)alloc((size_t)BWID * LRUD * 2);
  bf16*  Conv = (bf16*)alloc((size_t)NTOK * LRUD * 2);    // conv out; Hm alias later
  float* cA   = (float*)alloc((size_t)BATCHN * NCHUNK * LRUD * 4);
  float* cX   = (float*)alloc((size_t)BATCHN * NCHUNK * LRUD * 4);
  float* pref = (float*)alloc((size_t)BATCHN * NCHUNK * LRUD * 4);

  // ---- d_out doubles as scratch for two bf16 [NTOK][LRUD] buffers (exactly fits,
  // both dead before the final GEMM fully overwrites d_out with fp32 output)
  bf16* Yb = (bf16*)d_out;                                // gelu branch
  bf16* Xb = (bf16*)d_out + (size_t)NTOK * LRUD;          // x branch
  // aliases over dead buffers:
  bf16* Gx = Xbf;   // input-gate sigmoid; Xbf dead after GEMM2
  bf16* Ga = Xb;    // a-gate sigmoid;     Xb dead after conv
  bf16* Hm = Conv;  // h * y_branch;       scan3 reads conv[i] before writing hm[i]

  auto cvt = [&](const float* in, bf16* out, size_t n) {
    f32_to_bf16_kernel<<<dim3((unsigned)(n / 1024)), 256, 0, stream>>>(in, out, (int)n);
  };
  cvt(x_in, Xbf, (size_t)NTOK * HID);
  cvt(w_y,  Wyb, (size_t)LRUD * HID);
  cvt(w_x,  Wxb, (size_t)LRUD * HID);
  cvt(w_out, Wob, (size_t)HID * LRUD);
  cvt(ig_w, IGb, (size_t)BWID * LRUD);
  cvt(ag_w, AGb, (size_t)BWID * LRUD);

  // GEMM1: Yb = gelu(X @ w_y^T + b_y)
  gemm_kernel<1><<<dim3(LRUD / 128, NTOK / 128, 1), 256, 0, stream>>>(
      Xbf, HID, 0, Wyb, HID, 0, b_y, Yb, LRUD, 0, HID);
  // GEMM2: Xb = X @ w_x^T + b_x
  gemm_kernel<2><<<dim3(LRUD / 128, NTOK / 128, 1), 256, 0, stream>>>(
      Xbf, HID, 0, Wxb, HID, 0, b_x, Xb, LRUD, 0, HID);
  // depthwise causal conv
  conv_kernel<<<dim3(LRUD / 256, SEQL, BATCHN), 256, 0, stream>>>(Xb, conv_w, conv_b, Conv);
  // block-diagonal gates (per-head z): sigmoid epilogue
  gemm_kernel<3><<<dim3(BWID / 128, NTOK / 128, HEADSN), 256, 0, stream>>>(
      Conv, LRUD, BWID, IGb, BWID, (long long)BWID * BWID, ig_b, Gx, LRUD, BWID, BWID);
  gemm_kernel<3><<<dim3(BWID / 128, NTOK / 128, HEADSN), 256, 0, stream>>>(
      Conv, LRUD, BWID, AGb, BWID, (long long)BWID * BWID, ag_b, Ga, LRUD, BWID, BWID);
  // chunked parallel linear-recurrence scan (a,x recomputed in fp32 in both phases)
  scan1_kernel<<<dim3(LRUD / 256, NCHUNK, BATCHN), 256, 0, stream>>>(
      Conv, Gx, Ga, a_param, cA, cX);
  scan2_kernel<<<dim3((BATCHN * LRUD) / 256), 256, 0, stream>>>(cA, cX, prev_h, pref);
  scan3_kernel<<<dim3(LRUD / 256, NCHUNK, BATCHN), 256, 0, stream>>>(
      Conv, Gx, Ga, a_param, pref, Yb, Hm);
  // GEMM3: out = Hm @ w_out^T + b_out  (fp32 out, fully overwrites d_out)
  gemm_kernel<0><<<dim3(HID / 128, NTOK / 128, 1), 256, 0, stream>>>(
      Hm, LRUD, 0, Wob, LRUD, 0, b_out, (float*)d_out, HID, 0, LRUD);

  (void)in_sizes; (void)n_in; (void)out_size; (void)ws_size;
}